// Round 7
// baseline (292.071 us; speedup 1.0000x reference)
//
#include <hip/hip_runtime.h>
#include <math.h>

// ---------------------------------------------------------------------------
// HierarchicalVAE, MI355X (gfx950), fp32. One block per batch row, 128 blocks
// x 1024 threads, __launch_bounds__(1024,1) -> 16 waves/block = 4 waves/SIMD
// at <=128 VGPR (R6 proved the code fits in 128; R5's spills came from the
// bare launch_bounds(1024) defaulting to VGPR=64). Full pipeline per block,
// intermediates in LDS, float4 weight loads + split-K LDS reduction.
//
// Output layout (flat f32): rendered@0, mu@100352, logvar@108544,
// cp@116736, widths@124928, alphas@125184.
// ---------------------------------------------------------------------------

#define O_MU  100352
#define O_LV  108544
#define O_CP  116736
#define O_WD  124928
#define O_AL  125184

__device__ __forceinline__ float leaky(float x) {
    return x >= 0.0f ? x : 0.2f * x;
}
__device__ __forceinline__ float selu(float x) {
    const float scale = 1.0507009873554805f;
    const float alpha = 1.6732632423543772f;
    return x > 0.0f ? scale * x : scale * (alpha * expm1f(x));
}
__device__ __forceinline__ void fma4(float4& acc, float a, const float4 w) {
    acc.x = fmaf(a, w.x, acc.x);
    acc.y = fmaf(a, w.y, acc.y);
    acc.z = fmaf(a, w.z, acc.z);
    acc.w = fmaf(a, w.w, acc.w);
}
__device__ __forceinline__ void add4(float4& a, const float4 b) {
    a.x += b.x; a.y += b.y; a.z += b.z; a.w += b.w;
}

__global__ __launch_bounds__(1024, 1)
void pipeline(const float* __restrict__ x, const float* __restrict__ eps,
              const float* __restrict__ enc_w1, const float* __restrict__ enc_b1,
              const float* __restrict__ enc_w2, const float* __restrict__ enc_b2,
              const float* __restrict__ mu_w, const float* __restrict__ mu_b,
              const float* __restrict__ lv_w, const float* __restrict__ lv_b,
              const float* __restrict__ dec_w1, const float* __restrict__ dec_b1,
              const float* __restrict__ dec_w2, const float* __restrict__ dec_b2,
              const float* __restrict__ cp_w, const float* __restrict__ cp_b,
              const float* __restrict__ ref_w1, const float* __restrict__ ref_b1,
              const float* __restrict__ ref_w2, const float* __restrict__ ref_b2,
              const float* __restrict__ wd_w, const float* __restrict__ wd_b,
              const float* __restrict__ al_w, const float* __restrict__ al_b,
              float* __restrict__ out) {
    __shared__ __align__(16) float  sX[784];     // input row
    __shared__            float4 sPart4[1024];   // split-K partials (16 KB)
    __shared__ __align__(16) float  sH1[256];    // enc1 out
    __shared__ __align__(16) float  sHe[256];    // enc2 out
    __shared__ __align__(16) float  sML[128];    // mu | lv
    __shared__ __align__(16) float  sIn[96];     // h_in: z(64) | pts_norm(28)
    __shared__ __align__(16) float  sD1[512];    // dec1 out
    __shared__ __align__(16) float  sH2[512];    // dec2 out
    __shared__ __align__(16) float  sR1[512];    // ref1 out
    __shared__ __align__(16) float  sP[56];      // points (52)
    __shared__ __align__(16) float  sQ[128];     // polyline [p*64 + m*2 + d]
    __shared__            float  sWA[4];         // w0 w1 a0 a1

    const int row = blockIdx.x;
    const int tid = threadIdx.x;

    if (tid < 784) sX[tid] = x[row * 784 + tid];
    __syncthreads();

    // ---- enc1: 784 -> 256 leaky. 64 f4 cols x 16 K-groups, slice 49.
    {
        const int jv = tid & 63, g = tid >> 6;
        const float4* __restrict__ W4 = (const float4*)enc_w1;
        const int k0 = g * 49;
        float4 acc0 = {0,0,0,0}, acc1 = {0,0,0,0};
        fma4(acc0, sX[k0], W4[k0 * 64 + jv]);
#pragma unroll 6
        for (int i = 1; i < 49; i += 2) {
            fma4(acc0, sX[k0 + i + 0], W4[(k0 + i + 0) * 64 + jv]);
            fma4(acc1, sX[k0 + i + 1], W4[(k0 + i + 1) * 64 + jv]);
        }
        add4(acc0, acc1);
        sPart4[g * 64 + jv] = acc0;
    }
    __syncthreads();
    if (tid < 64) {
        float4 s = ((const float4*)enc_b1)[tid];
#pragma unroll
        for (int g = 0; g < 16; g++) add4(s, sPart4[g * 64 + tid]);
        s.x = leaky(s.x); s.y = leaky(s.y); s.z = leaky(s.z); s.w = leaky(s.w);
        ((float4*)sH1)[tid] = s;
    }
    __syncthreads();

    // ---- enc2: 256 -> 256 leaky. 64 f4 cols x 16 K-groups, slice 16 (4 f4 act reads).
    {
        const int jv = tid & 63, g = tid >> 6;
        const float4* __restrict__ W4 = (const float4*)enc_w2;
        const float4* __restrict__ A4 = (const float4*)sH1;
        const int k0 = g * 16;
        float4 acc0 = {0,0,0,0}, acc1 = {0,0,0,0};
#pragma unroll
        for (int i4 = 0; i4 < 4; i4++) {
            float4 a = A4[g * 4 + i4];
            fma4(acc0, a.x, W4[(k0 + i4 * 4 + 0) * 64 + jv]);
            fma4(acc1, a.y, W4[(k0 + i4 * 4 + 1) * 64 + jv]);
            fma4(acc0, a.z, W4[(k0 + i4 * 4 + 2) * 64 + jv]);
            fma4(acc1, a.w, W4[(k0 + i4 * 4 + 3) * 64 + jv]);
        }
        add4(acc0, acc1);
        sPart4[g * 64 + jv] = acc0;
    }
    __syncthreads();
    if (tid < 64) {
        float4 s = ((const float4*)enc_b2)[tid];
#pragma unroll
        for (int g = 0; g < 16; g++) add4(s, sPart4[g * 64 + tid]);
        s.x = leaky(s.x); s.y = leaky(s.y); s.z = leaky(s.z); s.w = leaky(s.w);
        ((float4*)sHe)[tid] = s;
    }
    __syncthreads();

    // ---- mu|lv: N=128 (mu|lv), 32 f4 cols x 32 K-groups, slice 8 (2 f4 act reads).
    {
        const int o4 = tid >> 5, g = tid & 31;
        const int jv = o4 & 15;
        const float4* __restrict__ W4 = (const float4*)(o4 < 16 ? mu_w : lv_w);
        const float4* __restrict__ A4 = (const float4*)sHe;
        const int k0 = g * 8;
        float4 acc = {0,0,0,0};
#pragma unroll
        for (int i4 = 0; i4 < 2; i4++) {
            float4 a = A4[g * 2 + i4];
            fma4(acc, a.x, W4[(k0 + i4 * 4 + 0) * 16 + jv]);
            fma4(acc, a.y, W4[(k0 + i4 * 4 + 1) * 16 + jv]);
            fma4(acc, a.z, W4[(k0 + i4 * 4 + 2) * 16 + jv]);
            fma4(acc, a.w, W4[(k0 + i4 * 4 + 3) * 16 + jv]);
        }
        sPart4[o4 * 32 + g] = acc;
    }
    __syncthreads();
    if (tid < 32) {
        const int jv = tid & 15;
        float4 s = (tid < 16) ? ((const float4*)mu_b)[jv] : ((const float4*)lv_b)[jv];
#pragma unroll
        for (int g = 0; g < 32; g++) add4(s, sPart4[tid * 32 + g]);
        ((float4*)sML)[tid] = s;  // mu(64) | lv(64)
        float4* o4p = (float4*)(out + (tid < 16 ? O_MU : O_LV) + row * 64);
        o4p[jv] = s;
    }
    __syncthreads();
    if (tid < 64)
        sIn[tid] = fmaf(eps[row * 64 + tid], expf(0.5f * sML[64 + tid]), sML[tid]);
    __syncthreads();

    // ---- dec1: 64 -> 512 selu. 128 f4 cols x 8 K-groups, slice 8 (2 f4 act reads).
    {
        const int jv = tid & 127, g = tid >> 7;
        const float4* __restrict__ W4 = (const float4*)dec_w1;
        const float4* __restrict__ A4 = (const float4*)sIn;
        const int k0 = g * 8;
        float4 acc = {0,0,0,0};
#pragma unroll
        for (int i4 = 0; i4 < 2; i4++) {
            float4 a = A4[g * 2 + i4];
            fma4(acc, a.x, W4[(k0 + i4 * 4 + 0) * 128 + jv]);
            fma4(acc, a.y, W4[(k0 + i4 * 4 + 1) * 128 + jv]);
            fma4(acc, a.z, W4[(k0 + i4 * 4 + 2) * 128 + jv]);
            fma4(acc, a.w, W4[(k0 + i4 * 4 + 3) * 128 + jv]);
        }
        sPart4[g * 128 + jv] = acc;
    }
    __syncthreads();
    if (tid < 128) {
        float4 s = ((const float4*)dec_b1)[tid];
#pragma unroll
        for (int g = 0; g < 8; g++) add4(s, sPart4[g * 128 + tid]);
        s.x = selu(s.x); s.y = selu(s.y); s.z = selu(s.z); s.w = selu(s.w);
        ((float4*)sD1)[tid] = s;
    }
    __syncthreads();

    // ---- dec2: 512 -> 512 selu. 128 f4 cols x 8 K-groups, slice 64 (16 f4 act reads).
    {
        const int jv = tid & 127, g = tid >> 7;
        const float4* __restrict__ W4 = (const float4*)dec_w2;
        const float4* __restrict__ A4 = (const float4*)sD1;
        const int k0 = g * 64;
        float4 acc0 = {0,0,0,0}, acc1 = {0,0,0,0};
#pragma unroll 4
        for (int i4 = 0; i4 < 16; i4++) {
            float4 a = A4[g * 16 + i4];
            fma4(acc0, a.x, W4[(k0 + i4 * 4 + 0) * 128 + jv]);
            fma4(acc1, a.y, W4[(k0 + i4 * 4 + 1) * 128 + jv]);
            fma4(acc0, a.z, W4[(k0 + i4 * 4 + 2) * 128 + jv]);
            fma4(acc1, a.w, W4[(k0 + i4 * 4 + 3) * 128 + jv]);
        }
        add4(acc0, acc1);
        sPart4[g * 128 + jv] = acc0;
    }
    __syncthreads();
    if (tid < 128) {
        float4 s = ((const float4*)dec_b2)[tid];
#pragma unroll
        for (int g = 0; g < 8; g++) add4(s, sPart4[g * 128 + tid]);
        s.x = selu(s.x); s.y = selu(s.y); s.z = selu(s.z); s.w = selu(s.w);
        ((float4*)sH2)[tid] = s;
    }
    __syncthreads();

    // ---- heads: 32 outputs x 32 lanes, K=512, stride 32.
    {
        const int o = tid >> 5, g = tid & 31;
        const float* __restrict__ W;
        int ldw, col;
        if (o < 28)      { W = cp_w; ldw = 28; col = o; }
        else if (o < 30) { W = wd_w; ldw = 2;  col = o - 28; }
        else             { W = al_w; ldw = 2;  col = o - 30; }
        float acc = 0.f;
        for (int k = g; k < 512; k += 32) acc = fmaf(sH2[k], W[k * ldw + col], acc);
        acc += __shfl_xor(acc, 1);
        acc += __shfl_xor(acc, 2);
        acc += __shfl_xor(acc, 4);
        acc += __shfl_xor(acc, 8);
        acc += __shfl_xor(acc, 16);
        if (g == 0) {
            if (o < 28) {
                sIn[64 + o] = tanhf(acc + cp_b[col]);          // pts_norm
            } else if (o < 30) {
                float v = 1.f / (1.f + expf(-(acc + wd_b[col])));
                v = fmaf(v, 2.f, 1.f);
                out[O_WD + row * 2 + col] = v;
                sWA[col] = v;
            } else {
                float v = 1.f / (1.f + expf(-(acc + al_b[col])));
                out[O_AL + row * 2 + col] = v;
                sWA[2 + col] = v;
            }
        }
    }
    __syncthreads();

    // ---- ref1: 92 -> 512 selu. 128 f4 cols x 8 K-groups, slice 12 (last 8).
    {
        const int jv = tid & 127, g = tid >> 7;
        const float4* __restrict__ W4 = (const float4*)ref_w1;
        const int k0 = g * 12;
        const int kend = (k0 + 12 < 92) ? (k0 + 12) : 92;
        float4 acc = {0,0,0,0};
        for (int k = k0; k < kend; k++)
            fma4(acc, sIn[k], W4[k * 128 + jv]);
        sPart4[g * 128 + jv] = acc;
    }
    __syncthreads();
    if (tid < 128) {
        float4 s = ((const float4*)ref_b1)[tid];
#pragma unroll
        for (int g = 0; g < 8; g++) add4(s, sPart4[g * 128 + tid]);
        s.x = selu(s.x); s.y = selu(s.y); s.z = selu(s.z); s.w = selu(s.w);
        ((float4*)sR1)[tid] = s;
    }
    __syncthreads();

    // ---- ref2: 52 outputs x 16 lanes, K=512 -> points.
    {
        const int o = tid >> 4, g = tid & 15;
        float acc = 0.f;
        if (o < 52)
            for (int k = g; k < 512; k += 16) acc = fmaf(sR1[k], ref_w2[k * 52 + o], acc);
        acc += __shfl_xor(acc, 1);
        acc += __shfl_xor(acc, 2);
        acc += __shfl_xor(acc, 4);
        acc += __shfl_xor(acc, 8);
        if (g == 0 && o < 52)
            sP[o] = fmaf(tanhf(acc + ref_b2[o]), 12.f, 14.f);  // *SCALE + HALF
    }
    __syncthreads();

    // ---- control_points out + bezier polyline q
    if (tid < 64) {
        int idx = tid;
        int p = idx >> 5, rest = idx & 31;
        int s = rest >> 3, kk = (rest >> 1) & 3, d = idx & 1;
        out[O_CP + row * 64 + idx] = sP[p * 26 + (3 * s + kk) * 2 + d];
    }
    if (tid < 128) {
        int idx = tid;
        int p = idx >> 6, s = (idx >> 4) & 3, ti = (idx >> 1) & 7, d = idx & 1;
        float t = (float)ti / 7.0f;
        float mt = 1.0f - t;
        float c0 = mt * mt * mt;
        float c1 = 3.f * mt * mt * t;
        float c2 = 3.f * mt * t * t;
        float c3 = t * t * t;
        const float* base = sP + p * 26 + (3 * s) * 2 + d;
        sQ[idx] = c0 * base[0] + c1 * base[2] + c2 * base[4] + c3 * base[6];
    }
    __syncthreads();

    // ---- raster: 784 px x 4 AA subsamples = 3136 units.
    const float2* __restrict__ sQ2 = (const float2*)sQ;
    for (int u = tid; u < 3136; u += 1024) {
        const int pixel = u >> 2;
        const int sub = u & 3;
        const int py = pixel / 28;
        const int px = pixel - py * 28;
        const float sy = ((float)(2 * py + (sub >> 1)) + 0.5f) * 0.5f;
        const float sx = ((float)(2 * px + (sub & 1)) + 0.5f) * 0.5f;
        float img = 1.0f;
#pragma unroll
        for (int p = 0; p < 2; p++) {
            float dmin2 = 1e30f;
            int cnt = 0;
            float2 cur = sQ2[p * 32];
            bool bp = cur.y > sy;
#pragma unroll
            for (int m = 0; m < 32; m++) {
                float2 nxt = sQ2[p * 32 + ((m + 1) & 31)];
                float dx = sx - cur.x;
                float dy = sy - cur.y;
                dmin2 = fminf(dmin2, fmaf(dx, dx, dy * dy));
                bool bn = nxt.y > sy;
                float den = nxt.y - cur.y + 1e-8f;
                float lhs = dx * den;
                float rhs = dy * (nxt.x - cur.x);
                if ((bp != bn) && ((lhs < rhs) == (den > 0.0f))) cnt++;
                cur = nxt;
                bp = bn;
            }
            float dist = sqrtf(dmin2);
            float stroke = fminf(fmaxf(fmaf(sWA[p], 0.5f, 0.5f) - dist, 0.f), 1.f);
            float cov = fmaxf((float)(cnt & 1), stroke);
            img *= fmaf(-sWA[2 + p], cov, 1.0f);
        }
        img += __shfl_xor(img, 1);
        img += __shfl_xor(img, 2);
        if (sub == 0) out[row * 784 + pixel] = 1.0f - 0.25f * img;
    }
}

extern "C" void kernel_launch(void* const* d_in, const int* in_sizes, int n_in,
                              void* d_out, int out_size, void* d_ws, size_t ws_size,
                              hipStream_t stream) {
    const float* x      = (const float*)d_in[0];
    const float* eps    = (const float*)d_in[1];
    const float* enc_w1 = (const float*)d_in[2];
    const float* enc_b1 = (const float*)d_in[3];
    const float* enc_w2 = (const float*)d_in[4];
    const float* enc_b2 = (const float*)d_in[5];
    const float* mu_w   = (const float*)d_in[6];
    const float* mu_b   = (const float*)d_in[7];
    const float* lv_w   = (const float*)d_in[8];
    const float* lv_b   = (const float*)d_in[9];
    const float* dec_w1 = (const float*)d_in[10];
    const float* dec_b1 = (const float*)d_in[11];
    const float* dec_w2 = (const float*)d_in[12];
    const float* dec_b2 = (const float*)d_in[13];
    const float* cp_w   = (const float*)d_in[14];
    const float* cp_b   = (const float*)d_in[15];
    const float* ref_w1 = (const float*)d_in[16];
    const float* ref_b1 = (const float*)d_in[17];
    const float* ref_w2 = (const float*)d_in[18];
    const float* ref_b2 = (const float*)d_in[19];
    const float* wd_w   = (const float*)d_in[20];
    const float* wd_b   = (const float*)d_in[21];
    const float* al_w   = (const float*)d_in[22];
    const float* al_b   = (const float*)d_in[23];

    float* out = (float*)d_out;

    pipeline<<<128, 1024, 0, stream>>>(x, eps, enc_w1, enc_b1, enc_w2, enc_b2,
                                       mu_w, mu_b, lv_w, lv_b, dec_w1, dec_b1,
                                       dec_w2, dec_b2, cp_w, cp_b, ref_w1, ref_b1,
                                       ref_w2, ref_b2, wd_w, wd_b, al_w, al_b,
                                       out);
}

// Round 8
// 216.766 us; speedup vs baseline: 1.3474x; 1.3474x over previous
//
#include <hip/hip_runtime.h>
#include <math.h>

// ---------------------------------------------------------------------------
// HierarchicalVAE, MI355X (gfx950), fp32. One block per batch row, 128 blocks
// x 512 threads, __launch_bounds__(512,1) (R6-proven: 128 VGPR, no spills;
// 1024-thread blocks force VGPR=64 + spills on this toolchain - R5/R7).
// R8: big layers stage weights via __builtin_amdgcn_global_load_lds into a
// 2x64KB LDS double buffer (m97-style 2-barrier K-loop) with per-row chunk
// rotation to kill cross-CU same-line L2 contention. Small layers as R6.
//
// Output layout (flat f32): rendered@0, mu@100352, logvar@108544,
// cp@116736, widths@124928, alphas@125184.
// ---------------------------------------------------------------------------

#define O_MU  100352
#define O_LV  108544
#define O_CP  116736
#define O_WD  124928
#define O_AL  125184

#define WBUF_STRIDE 16384   // floats per weight buffer slot (64 KB)

__device__ __forceinline__ float leaky(float x) {
    return x >= 0.0f ? x : 0.2f * x;
}
__device__ __forceinline__ float selu(float x) {
    const float scale = 1.0507009873554805f;
    const float alpha = 1.6732632423543772f;
    return x > 0.0f ? scale * x : scale * (alpha * expm1f(x));
}
template<int ACT>  // 1=leaky 2=selu
__device__ __forceinline__ float act_fn(float x) {
    if (ACT == 1) return leaky(x);
    if (ACT == 2) return selu(x);
    return x;
}
__device__ __forceinline__ void fma4(float4& acc, float a, const float4 w) {
    acc.x = fmaf(a, w.x, acc.x);
    acc.y = fmaf(a, w.y, acc.y);
    acc.z = fmaf(a, w.z, acc.z);
    acc.w = fmaf(a, w.w, acc.w);
}
__device__ __forceinline__ void add4(float4& a, const float4 b) {
    a.x += b.x; a.y += b.y; a.z += b.z; a.w += b.w;
}

// Async copy of one contiguous weight chunk (bytes % 1024 == 0) into LDS.
// Each wave moves 1 KB per instruction (64 lanes x 16 B), lds dest is
// wave-uniform base + lane*16 (HW rule). Completion drained by the
// compiler-emitted s_waitcnt vmcnt(0) before the next __syncthreads.
__device__ __forceinline__ void dma_chunk(const float* __restrict__ src,
                                          float* __restrict__ dst,
                                          int bytes, int tid) {
    const int lane = tid & 63;
    const int wave = tid >> 6;
    const char* s = (const char*)src + lane * 16;
    char* d = (char*)dst;
    for (int off = wave * 1024; off < bytes; off += 8192) {
        __builtin_amdgcn_global_load_lds(
            (const __attribute__((address_space(1))) unsigned int*)(s + off),
            (__attribute__((address_space(3))) unsigned int*)(d + off),
            16, 0, 0);
    }
}

// DMA-staged GEMM layer: out[N] = act(act_in[K] @ W[K,N] + b).
// Nv = N/4 f4-columns owned per thread; G = 512/Nv split-K groups whose
// partials reduce through sPart4. Chunks of CH K-rows double-buffered in
// sWbuf, processed in row-rotated order.
template<int K, int N, int CH, int ACT>
__device__ __forceinline__ void gemm_dma(const float* __restrict__ W,
                                         const float* __restrict__ bias,
                                         const float* __restrict__ actL,
                                         float* __restrict__ outL,
                                         float4* __restrict__ sPart4,
                                         float* __restrict__ sWbuf,
                                         int tid, int row) {
    constexpr int Nv = N / 4;
    constexpr int G  = 512 / Nv;
    constexpr int NC = (K + CH - 1) / CH;
    const int jv = tid & (Nv - 1);
    const int g  = tid / Nv;
    const int rot = row % NC;

    float4 acc = {0.f, 0.f, 0.f, 0.f};
    // prologue: DMA first (rotated) chunk into buffer 0
    {
        const int c = rot;
        const int rows = (c == NC - 1) ? (K - (NC - 1) * CH) : CH;
        dma_chunk(W + c * CH * N, sWbuf, rows * N * 4, tid);
    }
    __syncthreads();  // drains DMA; also orders actL producer
    for (int ci = 0; ci < NC; ci++) {
        int c = ci + rot; if (c >= NC) c -= NC;
        if (ci + 1 < NC) {
            int c2 = c + 1; if (c2 >= NC) c2 -= NC;
            const int rows2 = (c2 == NC - 1) ? (K - (NC - 1) * CH) : CH;
            dma_chunk(W + c2 * CH * N, sWbuf + ((ci + 1) & 1) * WBUF_STRIDE,
                      rows2 * N * 4, tid);
        }
        const int rows = (c == NC - 1) ? (K - (NC - 1) * CH) : CH;
        const int rpg = rows / G;
        const float4* __restrict__ Wl =
            (const float4*)(sWbuf + (ci & 1) * WBUF_STRIDE);
        const float* __restrict__ A = actL + c * CH + g * rpg;
        const int base = g * rpg * Nv + jv;
        for (int i = 0; i < rpg; i++)
            fma4(acc, A[i], Wl[i * Nv + base]);
        __syncthreads();  // buf swap safety + drains next-chunk DMA
    }
    sPart4[g * Nv + jv] = acc;
    __syncthreads();
    if (tid < Nv) {
        float4 s = ((const float4*)bias)[tid];
#pragma unroll
        for (int gg = 0; gg < G; gg++) add4(s, sPart4[gg * Nv + tid]);
        s.x = act_fn<ACT>(s.x); s.y = act_fn<ACT>(s.y);
        s.z = act_fn<ACT>(s.z); s.w = act_fn<ACT>(s.w);
        ((float4*)outL)[tid] = s;
    }
    __syncthreads();
}

__global__ __launch_bounds__(512, 1)
void pipeline(const float* __restrict__ x, const float* __restrict__ eps,
              const float* __restrict__ enc_w1, const float* __restrict__ enc_b1,
              const float* __restrict__ enc_w2, const float* __restrict__ enc_b2,
              const float* __restrict__ mu_w, const float* __restrict__ mu_b,
              const float* __restrict__ lv_w, const float* __restrict__ lv_b,
              const float* __restrict__ dec_w1, const float* __restrict__ dec_b1,
              const float* __restrict__ dec_w2, const float* __restrict__ dec_b2,
              const float* __restrict__ cp_w, const float* __restrict__ cp_b,
              const float* __restrict__ ref_w1, const float* __restrict__ ref_b1,
              const float* __restrict__ ref_w2, const float* __restrict__ ref_b2,
              const float* __restrict__ wd_w, const float* __restrict__ wd_b,
              const float* __restrict__ al_w, const float* __restrict__ al_b,
              float* __restrict__ out) {
    __shared__ __align__(16) float sWbuf[2 * WBUF_STRIDE];  // 128 KB weight dbuf
    __shared__ __align__(16) float sX[784];
    __shared__            float4 sPart4[512];               // 8 KB partials
    __shared__ __align__(16) float sH1[256];
    __shared__ __align__(16) float sHe[256];
    __shared__ __align__(16) float sML[128];
    __shared__ __align__(16) float sIn[96];                 // z(64) | pts_norm(28)
    __shared__ __align__(16) float sD1[512];
    __shared__ __align__(16) float sH2[512];
    __shared__ __align__(16) float sR1[512];
    __shared__ __align__(16) float sP[56];
    __shared__ __align__(16) float sQ[128];
    __shared__            float sWA[4];

    const int row = blockIdx.x;
    const int tid = threadIdx.x;

    for (int i = tid; i < 784; i += 512) sX[i] = x[row * 784 + i];
    // (enc1 prologue DMA is issued inside gemm_dma before the barrier)

    // ---- enc1: 784 -> 256 leaky. 14 chunks of 56 rows (57 KB each).
    gemm_dma<784, 256, 56, 1>(enc_w1, enc_b1, sX, sH1, sPart4, sWbuf, tid, row);

    // ---- enc2: 256 -> 256 leaky. 4 chunks of 64 rows (64 KB).
    gemm_dma<256, 256, 64, 1>(enc_w2, enc_b2, sH1, sHe, sPart4, sWbuf, tid, row);

    // ---- mu|lv: 32 f4 outputs x 16 K-groups, slice 16 (R6 form).
    {
        const int o4 = tid >> 4, g = tid & 15;
        const int jv = o4 & 15;
        const float4* __restrict__ W4 = (const float4*)(o4 < 16 ? mu_w : lv_w);
        const int k0 = g * 16;
        float4 acc = {0,0,0,0};
#pragma unroll
        for (int i = 0; i < 16; i++)
            fma4(acc, sHe[k0 + i], W4[(k0 + i) * 16 + jv]);
        sPart4[o4 * 16 + g] = acc;
    }
    __syncthreads();
    if (tid < 32) {
        const int jv = tid & 15;
        float4 s = (tid < 16) ? ((const float4*)mu_b)[jv] : ((const float4*)lv_b)[jv];
#pragma unroll
        for (int g = 0; g < 16; g++) add4(s, sPart4[tid * 16 + g]);
        ((float4*)sML)[tid] = s;  // mu(64) | lv(64)
        float4* o4p = (float4*)(out + (tid < 16 ? O_MU : O_LV) + row * 64);
        o4p[jv] = s;
    }
    __syncthreads();
    if (tid < 64)
        sIn[tid] = fmaf(eps[row * 64 + tid], expf(0.5f * sML[64 + tid]), sML[tid]);
    __syncthreads();

    // ---- dec1: 64 -> 512 selu. 128 f4 cols x 4 K-groups, slice 16 (R6 form).
    {
        const int jv = tid & 127, g = tid >> 7;
        const float4* __restrict__ W4 = (const float4*)dec_w1;
        const int k0 = g * 16;
        float4 acc = {0,0,0,0};
#pragma unroll
        for (int i = 0; i < 16; i++)
            fma4(acc, sIn[k0 + i], W4[(k0 + i) * 128 + jv]);
        sPart4[g * 128 + jv] = acc;
    }
    __syncthreads();
    if (tid < 128) {
        float4 s = ((const float4*)dec_b1)[tid];
#pragma unroll
        for (int g = 0; g < 4; g++) add4(s, sPart4[g * 128 + tid]);
        s.x = selu(s.x); s.y = selu(s.y); s.z = selu(s.z); s.w = selu(s.w);
        ((float4*)sD1)[tid] = s;
    }
    __syncthreads();

    // ---- dec2: 512 -> 512 selu. 16 chunks of 32 rows (64 KB).
    gemm_dma<512, 512, 32, 2>(dec_w2, dec_b2, sD1, sH2, sPart4, sWbuf, tid, row);

    // ---- heads: 32 outputs x 16 lanes, K=512 (R6 form).
    {
        const int o = tid >> 4, g = tid & 15;
        const float* __restrict__ W;
        int ldw, col;
        if (o < 28)      { W = cp_w; ldw = 28; col = o; }
        else if (o < 30) { W = wd_w; ldw = 2;  col = o - 28; }
        else             { W = al_w; ldw = 2;  col = o - 30; }
        float acc = 0.f;
        for (int k = g; k < 512; k += 16) acc = fmaf(sH2[k], W[k * ldw + col], acc);
        acc += __shfl_xor(acc, 1);
        acc += __shfl_xor(acc, 2);
        acc += __shfl_xor(acc, 4);
        acc += __shfl_xor(acc, 8);
        if (g == 0) {
            if (o < 28) {
                sIn[64 + o] = tanhf(acc + cp_b[col]);          // pts_norm
            } else if (o < 30) {
                float v = 1.f / (1.f + expf(-(acc + wd_b[col])));
                v = fmaf(v, 2.f, 1.f);
                out[O_WD + row * 2 + col] = v;
                sWA[col] = v;
            } else {
                float v = 1.f / (1.f + expf(-(acc + al_b[col])));
                out[O_AL + row * 2 + col] = v;
                sWA[2 + col] = v;
            }
        }
    }
    __syncthreads();

    // ---- ref1: 92 -> 512 selu. chunks {32,32,28} (64/64/57 KB).
    gemm_dma<92, 512, 32, 2>(ref_w1, ref_b1, sIn, sR1, sPart4, sWbuf, tid, row);

    // ---- ref2: 52 outputs x 8 lanes, K=512 -> points (R6 form).
    {
        const int o = tid >> 3, g = tid & 7;
        float acc = 0.f;
        if (o < 52)
            for (int k = g; k < 512; k += 8) acc = fmaf(sR1[k], ref_w2[k * 52 + o], acc);
        acc += __shfl_xor(acc, 1);
        acc += __shfl_xor(acc, 2);
        acc += __shfl_xor(acc, 4);
        if (g == 0 && o < 52)
            sP[o] = fmaf(tanhf(acc + ref_b2[o]), 12.f, 14.f);  // *SCALE + HALF
    }
    __syncthreads();

    // ---- control_points out + bezier polyline q
    if (tid < 64) {
        int idx = tid;
        int p = idx >> 5, rest = idx & 31;
        int s = rest >> 3, kk = (rest >> 1) & 3, d = idx & 1;
        out[O_CP + row * 64 + idx] = sP[p * 26 + (3 * s + kk) * 2 + d];
    }
    if (tid < 128) {
        int idx = tid;
        int p = idx >> 6, s = (idx >> 4) & 3, ti = (idx >> 1) & 7, d = idx & 1;
        float t = (float)ti / 7.0f;
        float mt = 1.0f - t;
        float c0 = mt * mt * mt;
        float c1 = 3.f * mt * mt * t;
        float c2 = 3.f * mt * t * t;
        float c3 = t * t * t;
        const float* base = sP + p * 26 + (3 * s) * 2 + d;
        sQ[idx] = c0 * base[0] + c1 * base[2] + c2 * base[4] + c3 * base[6];
    }
    __syncthreads();

    // ---- raster: 784 px x 4 AA subsamples = 3136 units.
    const float2* __restrict__ sQ2 = (const float2*)sQ;
    for (int u = tid; u < 3136; u += 512) {
        const int pixel = u >> 2;
        const int sub = u & 3;
        const int py = pixel / 28;
        const int px = pixel - py * 28;
        const float sy = ((float)(2 * py + (sub >> 1)) + 0.5f) * 0.5f;
        const float sx = ((float)(2 * px + (sub & 1)) + 0.5f) * 0.5f;
        float img = 1.0f;
#pragma unroll
        for (int p = 0; p < 2; p++) {
            float dmin2 = 1e30f;
            int cnt = 0;
            float2 cur = sQ2[p * 32];
            bool bp = cur.y > sy;
#pragma unroll
            for (int m = 0; m < 32; m++) {
                float2 nxt = sQ2[p * 32 + ((m + 1) & 31)];
                float dx = sx - cur.x;
                float dy = sy - cur.y;
                dmin2 = fminf(dmin2, fmaf(dx, dx, dy * dy));
                bool bn = nxt.y > sy;
                float den = nxt.y - cur.y + 1e-8f;
                float lhs = dx * den;
                float rhs = dy * (nxt.x - cur.x);
                if ((bp != bn) && ((lhs < rhs) == (den > 0.0f))) cnt++;
                cur = nxt;
                bp = bn;
            }
            float dist = sqrtf(dmin2);
            float stroke = fminf(fmaxf(fmaf(sWA[p], 0.5f, 0.5f) - dist, 0.f), 1.f);
            float cov = fmaxf((float)(cnt & 1), stroke);
            img *= fmaf(-sWA[2 + p], cov, 1.0f);
        }
        img += __shfl_xor(img, 1);
        img += __shfl_xor(img, 2);
        if (sub == 0) out[row * 784 + pixel] = 1.0f - 0.25f * img;
    }
}

extern "C" void kernel_launch(void* const* d_in, const int* in_sizes, int n_in,
                              void* d_out, int out_size, void* d_ws, size_t ws_size,
                              hipStream_t stream) {
    const float* x      = (const float*)d_in[0];
    const float* eps    = (const float*)d_in[1];
    const float* enc_w1 = (const float*)d_in[2];
    const float* enc_b1 = (const float*)d_in[3];
    const float* enc_w2 = (const float*)d_in[4];
    const float* enc_b2 = (const float*)d_in[5];
    const float* mu_w   = (const float*)d_in[6];
    const float* mu_b   = (const float*)d_in[7];
    const float* lv_w   = (const float*)d_in[8];
    const float* lv_b   = (const float*)d_in[9];
    const float* dec_w1 = (const float*)d_in[10];
    const float* dec_b1 = (const float*)d_in[11];
    const float* dec_w2 = (const float*)d_in[12];
    const float* dec_b2 = (const float*)d_in[13];
    const float* cp_w   = (const float*)d_in[14];
    const float* cp_b   = (const float*)d_in[15];
    const float* ref_w1 = (const float*)d_in[16];
    const float* ref_b1 = (const float*)d_in[17];
    const float* ref_w2 = (const float*)d_in[18];
    const float* ref_b2 = (const float*)d_in[19];
    const float* wd_w   = (const float*)d_in[20];
    const float* wd_b   = (const float*)d_in[21];
    const float* al_w   = (const float*)d_in[22];
    const float* al_b   = (const float*)d_in[23];

    float* out = (float*)d_out;

    pipeline<<<128, 512, 0, stream>>>(x, eps, enc_w1, enc_b1, enc_w2, enc_b2,
                                      mu_w, mu_b, lv_w, lv_b, dec_w1, dec_b1,
                                      dec_w2, dec_b2, cp_w, cp_b, ref_w1, ref_b1,
                                      ref_w2, ref_b2, wd_w, wd_b, al_w, al_b,
                                      out);
}